// Round 4
// baseline (91.864 us; speedup 1.0000x reference)
//
#include <hip/hip_runtime.h>
#include <hip/hip_bf16.h>
#include <stdint.h>

#define BB 8
#define TT 2048
#define CC 768
#define HH 64

typedef __bf16 bf16x8 __attribute__((ext_vector_type(8)));
typedef float f32x4 __attribute__((ext_vector_type(4)));

__device__ inline __bf16 f2b(float f) {
    __hip_bfloat16 h = __float2bfloat16(f);
    return __builtin_bit_cast(__bf16, h);
}
__device__ inline ushort f2bits(float f) {
    __hip_bfloat16 h = __float2bfloat16(f);
    return __builtin_bit_cast(ushort, h);
}

// ---------------- Kernel 0: W transpose to bf16 [3][64][768] -------------
__launch_bounds__(256)
__global__ void wt_kernel(const float* __restrict__ Wk, const float* __restrict__ Wq,
                          const float* __restrict__ Wv, ushort* __restrict__ Wt) {
    __shared__ float tile[64][65];
    int m  = blockIdx.x / 12;
    int c0 = (blockIdx.x % 12) * 64;
    const float* W = (m == 0) ? Wq : ((m == 1) ? Wk : Wv);
    int tid = threadIdx.x;
#pragma unroll
    for (int i = 0; i < 4; i++) {
        int r   = (tid >> 4) + i * 16;
        int col = (tid & 15) * 4;
        float4 v = *(const float4*)&W[(size_t)(c0 + r) * 64 + col];
        tile[r][col] = v.x; tile[r][col + 1] = v.y;
        tile[r][col + 2] = v.z; tile[r][col + 3] = v.w;
    }
    __syncthreads();
    int j  = tid >> 2;
    int cc = (tid & 3) * 16;
    ushort tmp[16];
#pragma unroll
    for (int e = 0; e < 16; e++) tmp[e] = f2bits(tile[cc + e][j]);
    ushort* dst = &Wt[(size_t)(m * 64 + j) * CC + c0 + cc];
    *(uint4*)(dst)     = *(uint4*)&tmp[0];
    *(uint4*)(dst + 8) = *(uint4*)&tmp[8];
}

// ---------------- Kernel 1: QKV projection GEMM --------------------------
// Block: 16 rows x 192 cols, 4 waves; wave w owns cols [w*48,+48).
// BK=128 double-buffered LDS x-tile (bf16, XOR-swizzled 16B chunks).
// Grid = 16384/16 = 1024 (4 blocks/CU -> 16 waves/CU in flight).
__launch_bounds__(256)
__global__ void qkv_kernel(const float* __restrict__ x, const ushort* __restrict__ Wt,
                           ushort* __restrict__ qws, ushort* __restrict__ kws,
                           ushort* __restrict__ vws) {
    __shared__ ushort xs[2][16][128];   // 4KB per buffer

    int tid  = threadIdx.x;
    int wid  = tid >> 6;
    int lane = tid & 63;
    int l15  = lane & 15;
    int hi4  = lane >> 4;
    int row0 = blockIdx.x * 16;

    // staging: thread -> (row = tid>>4, one 16-elem chunk c = tid&15)
    int srow = tid >> 4;
    int c0   = tid & 15;
    int sw   = srow & 7;
    const float* xp = x + (size_t)(row0 + srow) * CC + c0 * 8;

    const ushort* wtp[3];
#pragma unroll
    for (int nt = 0; nt < 3; nt++)
        wtp[nt] = Wt + (size_t)(wid * 48 + nt * 16 + l15) * CC + hi4 * 8;

    f32x4 acc[3];
#pragma unroll
    for (int nt = 0; nt < 3; nt++) acc[nt] = (f32x4){0.f, 0.f, 0.f, 0.f};

    float4 p0, p1;
    auto ld = [&](int kc) {
        p0 = *(const float4*)(xp + kc);
        p1 = *(const float4*)(xp + kc + 4);
    };
    auto wr = [&](int buf) {
        ushort e[8];
        e[0] = f2bits(p0.x); e[1] = f2bits(p0.y); e[2] = f2bits(p0.z); e[3] = f2bits(p0.w);
        e[4] = f2bits(p1.x); e[5] = f2bits(p1.y); e[6] = f2bits(p1.z); e[7] = f2bits(p1.w);
        *(uint4*)&xs[buf][srow][(c0 ^ sw) * 8] = *(uint4*)&e[0];
    };

    ld(0);
    wr(0);
    int cur = 0;
    for (int t = 0; t < 6; t++) {
        __syncthreads();
        if (t < 5) ld((t + 1) * 128);     // next-chunk loads hide under compute
        int kc = t * 128;
#pragma unroll
        for (int ks = 0; ks < 4; ks++) {
            int ch = ((ks * 4 + hi4) ^ (l15 & 7)) * 8;
            bf16x8 a = __builtin_bit_cast(bf16x8, *(const uint4*)&xs[cur][l15][ch]);
#pragma unroll
            for (int nt = 0; nt < 3; nt++) {
                bf16x8 b = __builtin_bit_cast(bf16x8, *(const uint4*)(wtp[nt] + kc + ks * 32));
                acc[nt] = __builtin_amdgcn_mfma_f32_16x16x32_bf16(a, b, acc[nt], 0, 0, 0);
            }
        }
        if (t < 5) { wr(cur ^ 1); cur ^= 1; }
    }

    int r0   = row0 + 4 * hi4;
    int bidx = row0 >> 11;
    int t0   = r0 & 2047;
#pragma unroll
    for (int nt = 0; nt < 3; nt++) {
        int c = wid * 48 + nt * 16 + l15;
        int m = c >> 6;
        int j = c & 63;
        if (m == 0) {
#pragma unroll
            for (int r = 0; r < 4; r++)
                qws[(size_t)(r0 + r) * 64 + j] = f2bits(acc[nt][r]);
        } else if (m == 1) {
#pragma unroll
            for (int r = 0; r < 4; r++)
                kws[(size_t)(r0 + r) * 64 + j] = f2bits(acc[nt][r]);
        } else {
            ushort4 pk;
            pk.x = f2bits(acc[nt][0]);
            pk.y = f2bits(acc[nt][1]);
            pk.z = f2bits(acc[nt][2]);
            pk.w = f2bits(acc[nt][3]);
            *(ushort4*)&vws[((size_t)bidx * 64 + j) * TT + t0] = pk;
        }
    }
}

// ---------------- Kernel 2: flash attention, wave-task decomposition -----
// Wave-task = (b, 16-row q-tile, 256-row KV segment). 4608 tasks, grid 1152.
// Defer-max (T13) + deferred l-reduction; K+V loads issued at iteration top.
#define NTPB 576
__launch_bounds__(256)
__global__ void flash_kernel(const ushort* __restrict__ qg, const ushort* __restrict__ kg,
                             const ushort* __restrict__ vtg, float* __restrict__ out,
                             float* __restrict__ pO, float* __restrict__ pM,
                             float* __restrict__ pL) {
    __shared__ ushort Ps[4][16][72];

    int wid  = threadIdx.x >> 6;
    int lane = threadIdx.x & 63;
    int l15  = lane & 15;
    int hi4  = lane >> 4;
    int koff = hi4 * 8;

    int gw = blockIdx.x * 4 + wid;
    int b  = gw / NTPB;
    int tp = gw - b * NTPB;
    int g  = 0;
    while (tp >= 8 * (g + 1) * (g + 2)) g++;
    int r_    = tp - 8 * g * (g + 1);
    int qt    = 16 * g + r_ / (g + 1);
    int seg   = r_ - (qt - 16 * g) * (g + 1);
    int nseg  = g + 1;
    int qmin  = qt * 16;
    int s_beg = seg * 256;
    int s_end = s_beg + 256 < qmin + 16 ? s_beg + 256 : qmin + 16;

    const ushort* qp = qg + ((size_t)b * TT + qmin + l15) * 64 + koff;
    bf16x8 qf0 = __builtin_bit_cast(bf16x8, *(const uint4*)qp);
    bf16x8 qf1 = __builtin_bit_cast(bf16x8, *(const uint4*)(qp + 32));

    f32x4 o[4];
#pragma unroll
    for (int i = 0; i < 4; i++) o[i] = (f32x4){0.f, 0.f, 0.f, 0.f};
    float mrun[4], lpart[4];
#pragma unroll
    for (int r = 0; r < 4; r++) { mrun[r] = -INFINITY; lpart[r] = 0.f; }

    const float scale = 0.125f;

    for (int s0 = s_beg; s0 < s_end; s0 += 64) {
        bool maskt = (s0 + 63 > qmin);

        // ---- issue ALL K loads, then ALL V loads (V stays in flight) ----
        bf16x8 kf[4][2];
#pragma unroll
        for (int nt = 0; nt < 4; nt++) {
            const ushort* kp = kg + ((size_t)b * TT + s0 + nt * 16 + l15) * 64 + koff;
            kf[nt][0] = __builtin_bit_cast(bf16x8, *(const uint4*)kp);
            kf[nt][1] = __builtin_bit_cast(bf16x8, *(const uint4*)(kp + 32));
        }
        bf16x8 vf[4][2];
#pragma unroll
        for (int nth = 0; nth < 4; nth++) {
            const ushort* vbase = vtg + ((size_t)b * 64 + nth * 16 + l15) * TT + s0;
            vf[nth][0] = __builtin_bit_cast(bf16x8, *(const uint4*)(vbase + koff));
            vf[nth][1] = __builtin_bit_cast(bf16x8, *(const uint4*)(vbase + 32 + koff));
        }

        float sv[4][4];
        __builtin_amdgcn_s_setprio(1);
#pragma unroll
        for (int nt = 0; nt < 4; nt++) {
            f32x4 s = (f32x4){0.f, 0.f, 0.f, 0.f};
            s = __builtin_amdgcn_mfma_f32_16x16x32_bf16(qf0, kf[nt][0], s, 0, 0, 0);
            s = __builtin_amdgcn_mfma_f32_16x16x32_bf16(qf1, kf[nt][1], s, 0, 0, 0);
#pragma unroll
            for (int r = 0; r < 4; r++) {
                float v = s[r] * scale;
                if (maskt) {
                    int krow = s0 + nt * 16 + l15;
                    int qgl  = qmin + 4 * hi4 + r;
                    if (krow > qgl) v = -INFINITY;
                }
                sv[nt][r] = v;
            }
        }
        __builtin_amdgcn_s_setprio(0);

        // ---- defer-max: rescale only when a row's max grew past m+8 ----
        float lmax[4];
#pragma unroll
        for (int r = 0; r < 4; r++)
            lmax[r] = fmaxf(fmaxf(sv[0][r], sv[1][r]), fmaxf(sv[2][r], sv[3][r]));
        bool need = (lmax[0] > mrun[0] + 8.f) || (lmax[1] > mrun[1] + 8.f) ||
                    (lmax[2] > mrun[2] + 8.f) || (lmax[3] > mrun[3] + 8.f);
        if (__any(need)) {
#pragma unroll
            for (int r = 0; r < 4; r++) {
                float tmax = lmax[r];
#pragma unroll
                for (int off = 1; off < 16; off <<= 1)
                    tmax = fmaxf(tmax, __shfl_xor(tmax, off));
                float mnew  = fmaxf(mrun[r], tmax);
                float alpha = __expf(mrun[r] - mnew);
                lpart[r] *= alpha;
#pragma unroll
                for (int nth = 0; nth < 4; nth++) o[nth][r] *= alpha;
                mrun[r] = mnew;
            }
        }

        // ---- exp + partial row-sum + P -> LDS ----
#pragma unroll
        for (int r = 0; r < 4; r++) {
            int prow = 4 * hi4 + r;
#pragma unroll
            for (int nt = 0; nt < 4; nt++) {
                float p = __expf(sv[nt][r] - mrun[r]);
                lpart[r] += p;
                Ps[wid][prow][nt * 16 + l15] = f2bits(p);
            }
        }

        bf16x8 pf0 = __builtin_bit_cast(bf16x8, *(const uint4*)&Ps[wid][l15][koff]);
        bf16x8 pf1 = __builtin_bit_cast(bf16x8, *(const uint4*)&Ps[wid][l15][32 + koff]);
        __builtin_amdgcn_s_setprio(1);
#pragma unroll
        for (int nth = 0; nth < 4; nth++) {
            o[nth] = __builtin_amdgcn_mfma_f32_16x16x32_bf16(pf0, vf[nth][0], o[nth], 0, 0, 0);
            o[nth] = __builtin_amdgcn_mfma_f32_16x16x32_bf16(pf1, vf[nth][1], o[nth], 0, 0, 0);
        }
        __builtin_amdgcn_s_setprio(0);
    }

    // final l reduction (once per task)
    float lrun[4];
#pragma unroll
    for (int r = 0; r < 4; r++) {
        float s = lpart[r];
#pragma unroll
        for (int off = 1; off < 16; off <<= 1)
            s += __shfl_xor(s, off);
        lrun[r] = s;
    }

    if (nseg == 1) {
        float inv[4];
#pragma unroll
        for (int r = 0; r < 4; r++) inv[r] = 1.0f / lrun[r];
#pragma unroll
        for (int nth = 0; nth < 4; nth++)
#pragma unroll
            for (int r = 0; r < 4; r++) {
                int row = qmin + 4 * hi4 + r;
                out[((size_t)b * TT + row) * 64 + nth * 16 + l15] = o[nth][r] * inv[r];
            }
    } else {
        size_t tb = (size_t)(b * NTPB + tp);
#pragma unroll
        for (int nth = 0; nth < 4; nth++)
#pragma unroll
            for (int r = 0; r < 4; r++) {
                int row = 4 * hi4 + r;
                pO[tb * 1024 + row * 64 + nth * 16 + l15] = o[nth][r];
            }
        if (l15 == 0) {
#pragma unroll
            for (int r = 0; r < 4; r++) {
                int row = 4 * hi4 + r;
                pM[tb * 16 + row] = mrun[r];
                pL[tb * 16 + row] = lrun[r];
            }
        }
    }
}

// ---------------- Kernel 3: merge partials for qt >= 16 ------------------
__launch_bounds__(256)
__global__ void merge_kernel(const float* __restrict__ pO, const float* __restrict__ pM,
                             const float* __restrict__ pL, float* __restrict__ out) {
    int b  = blockIdx.x / 112;
    int qt = 16 + (blockIdx.x % 112);
    int g  = qt >> 4;
    int nseg  = g + 1;
    int tbase = b * NTPB + 8 * g * (g + 1) + (qt - 16 * g) * (g + 1);
    int row = threadIdx.x >> 4;
    int col = (threadIdx.x & 15) * 4;

    float mstar = -INFINITY;
    for (int s = 0; s < nseg; s++)
        mstar = fmaxf(mstar, pM[(size_t)(tbase + s) * 16 + row]);
    float4 oa = {0.f, 0.f, 0.f, 0.f};
    float la = 0.f;
    for (int s = 0; s < nseg; s++) {
        float w = __expf(pM[(size_t)(tbase + s) * 16 + row] - mstar);
        la += w * pL[(size_t)(tbase + s) * 16 + row];
        float4 ov = *(const float4*)&pO[(size_t)(tbase + s) * 1024 + row * 64 + col];
        oa.x += w * ov.x; oa.y += w * ov.y; oa.z += w * ov.z; oa.w += w * ov.w;
    }
    float inv = 1.0f / la;
    float4 res = {oa.x * inv, oa.y * inv, oa.z * inv, oa.w * inv};
    *(float4*)&out[((size_t)b * TT + qt * 16 + row) * 64 + col] = res;
}

// ---------------- launch --------------------------------------------------
extern "C" void kernel_launch(void* const* d_in, const int* in_sizes, int n_in,
                              void* d_out, int out_size, void* d_ws, size_t ws_size,
                              hipStream_t stream) {
    const float* x  = (const float*)d_in[0];
    const float* Wk = (const float*)d_in[1];
    const float* Wq = (const float*)d_in[2];
    const float* Wv = (const float*)d_in[3];
    float* out = (float*)d_out;

    char* ws = (char*)d_ws;
    ushort* Wt  = (ushort*)(ws);
    ushort* qws = (ushort*)(ws + 0x50000);
    ushort* kws = (ushort*)(ws + 0x250000);
    ushort* vws = (ushort*)(ws + 0x450000);
    float*  pO  = (float*)(ws + 0x650000);
    float*  pM  = (float*)(ws + 0x1850000);
    float*  pL  = (float*)(ws + 0x1898000);

    wt_kernel<<<36, 256, 0, stream>>>(Wk, Wq, Wv, Wt);
    qkv_kernel<<<(BB * TT) / 16, 256, 0, stream>>>(x, Wt, qws, kws, vws);
    flash_kernel<<<(BB * NTPB) / 4, 256, 0, stream>>>(qws, kws, vws, out, pO, pM, pL);
    merge_kernel<<<BB * 112, 256, 0, stream>>>(pO, pM, pL, out);
}

// Round 5
// 83.516 us; speedup vs baseline: 1.1000x; 1.1000x over previous
//
#include <hip/hip_runtime.h>
#include <hip/hip_bf16.h>
#include <stdint.h>

#define BB 8
#define TT 2048
#define CC 768
#define HH 64

typedef __bf16 bf16x8 __attribute__((ext_vector_type(8)));
typedef float f32x4 __attribute__((ext_vector_type(4)));

__device__ inline ushort f2bits(float f) {
    __hip_bfloat16 h = __float2bfloat16(f);
    return __builtin_bit_cast(ushort, h);
}
__device__ inline float bits2f(ushort u) {
    return __builtin_bit_cast(float, ((uint32_t)u) << 16);
}
// barrier that does NOT drain vmcnt: LDS-visibility only
__device__ inline void lds_barrier() {
    asm volatile("s_waitcnt lgkmcnt(0)" ::: "memory");
    __builtin_amdgcn_s_barrier();
    asm volatile("" ::: "memory");
}

// ---------------- Kernel 0: W transpose to bf16 [3][64][768] -------------
__launch_bounds__(256)
__global__ void wt_kernel(const float* __restrict__ Wk, const float* __restrict__ Wq,
                          const float* __restrict__ Wv, ushort* __restrict__ Wt) {
    __shared__ float tile[64][65];
    int m  = blockIdx.x / 12;
    int c0 = (blockIdx.x % 12) * 64;
    const float* W = (m == 0) ? Wq : ((m == 1) ? Wk : Wv);
    int tid = threadIdx.x;
#pragma unroll
    for (int i = 0; i < 4; i++) {
        int r   = (tid >> 4) + i * 16;
        int col = (tid & 15) * 4;
        float4 v = *(const float4*)&W[(size_t)(c0 + r) * 64 + col];
        tile[r][col] = v.x; tile[r][col + 1] = v.y;
        tile[r][col + 2] = v.z; tile[r][col + 3] = v.w;
    }
    __syncthreads();
    int j  = tid >> 2;
    int cc = (tid & 3) * 16;
    ushort tmp[16];
#pragma unroll
    for (int e = 0; e < 16; e++) tmp[e] = f2bits(tile[cc + e][j]);
    ushort* dst = &Wt[(size_t)(m * 64 + j) * CC + c0 + cc];
    *(uint4*)(dst)     = *(uint4*)&tmp[0];
    *(uint4*)(dst + 8) = *(uint4*)&tmp[8];
}

// ---------------- Kernel 1: QKV projection GEMM --------------------------
// Block: 32 rows x 192 cols, 4 waves; wave w owns cols [w*48,+48), 2 row tiles.
// BK=128, LDS double-buffer + register double-buffer (loads issued 2 steps
// ahead); raw s_barrier (lgkm-only) so global loads stay in flight.
__launch_bounds__(256)
__global__ void qkv_kernel(const float* __restrict__ x, const ushort* __restrict__ Wt,
                           ushort* __restrict__ qws, ushort* __restrict__ kws,
                           ushort* __restrict__ vws) {
    __shared__ ushort xs[2][32][128];   // 8KB x2

    int tid  = threadIdx.x;
    int wid  = tid >> 6;
    int lane = tid & 63;
    int l15  = lane & 15;
    int hi4  = lane >> 4;
    int row0 = blockIdx.x * 32;

    // staging: thread -> row = tid>>3 (0..31), 16 elems at (tid&7)*16
    int srow = tid >> 3;
    int c0   = (tid & 7) * 2;          // even 16B-chunk index
    int sw   = srow & 7;
    const float* xp = x + (size_t)(row0 + srow) * CC + (tid & 7) * 16;

    const ushort* wtp[3];
#pragma unroll
    for (int nt = 0; nt < 3; nt++)
        wtp[nt] = Wt + (size_t)(wid * 48 + nt * 16 + l15) * CC + hi4 * 8;

    f32x4 acc[2][3];
#pragma unroll
    for (int mm = 0; mm < 2; mm++)
#pragma unroll
        for (int nt = 0; nt < 3; nt++) acc[mm][nt] = (f32x4){0.f, 0.f, 0.f, 0.f};

    float4 pA[4], pB[4];
    auto ld = [&](float4* p, int t) {
        const float* s = xp + t * 128;
        p[0] = *(const float4*)(s);
        p[1] = *(const float4*)(s + 4);
        p[2] = *(const float4*)(s + 8);
        p[3] = *(const float4*)(s + 12);
    };
    auto wr = [&](const float4* p, int buf) {
        ushort lo[8], hi[8];
        lo[0] = f2bits(p[0].x); lo[1] = f2bits(p[0].y); lo[2] = f2bits(p[0].z); lo[3] = f2bits(p[0].w);
        lo[4] = f2bits(p[1].x); lo[5] = f2bits(p[1].y); lo[6] = f2bits(p[1].z); lo[7] = f2bits(p[1].w);
        hi[0] = f2bits(p[2].x); hi[1] = f2bits(p[2].y); hi[2] = f2bits(p[2].z); hi[3] = f2bits(p[2].w);
        hi[4] = f2bits(p[3].x); hi[5] = f2bits(p[3].y); hi[6] = f2bits(p[3].z); hi[7] = f2bits(p[3].w);
        *(uint4*)&xs[buf][srow][((c0)     ^ sw) * 8] = *(uint4*)&lo[0];
        *(uint4*)&xs[buf][srow][((c0 + 1) ^ sw) * 8] = *(uint4*)&hi[0];
    };
    auto compute = [&](int buf) {
#pragma unroll
        for (int ks = 0; ks < 4; ks++) {
            int ch = ((ks * 4 + hi4) ^ (l15 & 7)) * 8;
            bf16x8 a0 = __builtin_bit_cast(bf16x8, *(const uint4*)&xs[buf][l15][ch]);
            bf16x8 a1 = __builtin_bit_cast(bf16x8, *(const uint4*)&xs[buf][16 + l15][ch]);
#pragma unroll
            for (int nt = 0; nt < 3; nt++) {
                bf16x8 b = __builtin_bit_cast(bf16x8, *(const uint4*)(wtp[nt] + ks * 32));
                acc[0][nt] = __builtin_amdgcn_mfma_f32_16x16x32_bf16(a0, b, acc[0][nt], 0, 0, 0);
                acc[1][nt] = __builtin_amdgcn_mfma_f32_16x16x32_bf16(a1, b, acc[1][nt], 0, 0, 0);
            }
#pragma unroll
            for (int nt = 0; nt < 3; nt++) wtp[nt] += 0;  // keep pointers
        }
#pragma unroll
        for (int nt = 0; nt < 3; nt++) wtp[nt] += 128;
    };

    // prologue: chunk0 -> pA -> buf0 ; chunk1 -> pB
    ld(pA, 0);
    ld(pB, 1);
    wr(pA, 0);
    // steps t=0..5 ; even t: compute buf0, stage pB->buf1, load pA(t+2)
#pragma unroll
    for (int t = 0; t < 6; t++) {
        lds_barrier();
        compute(t & 1);
        if (t < 5) wr((t & 1) ? pA : pB, (t & 1) ^ 1);
        if (t < 4) ld((t & 1) ? pB : pA, t + 2);
    }

    // epilogue: q,k row-major bf16; v transposed [b][h][t]
    int bidx = row0 >> 11;
#pragma unroll
    for (int mm = 0; mm < 2; mm++) {
        int r0 = row0 + mm * 16 + 4 * hi4;
        int t0 = r0 & 2047;
#pragma unroll
        for (int nt = 0; nt < 3; nt++) {
            int c = wid * 48 + nt * 16 + l15;
            int m = c >> 6;
            int j = c & 63;
            if (m == 0) {
#pragma unroll
                for (int r = 0; r < 4; r++)
                    qws[(size_t)(r0 + r) * 64 + j] = f2bits(acc[mm][nt][r]);
            } else if (m == 1) {
#pragma unroll
                for (int r = 0; r < 4; r++)
                    kws[(size_t)(r0 + r) * 64 + j] = f2bits(acc[mm][nt][r]);
            } else {
                ushort4 pk;
                pk.x = f2bits(acc[mm][nt][0]);
                pk.y = f2bits(acc[mm][nt][1]);
                pk.z = f2bits(acc[mm][nt][2]);
                pk.w = f2bits(acc[mm][nt][3]);
                *(ushort4*)&vws[((size_t)bidx * 64 + j) * TT + t0] = pk;
            }
        }
    }
}

// ---------------- Kernel 2: flash attention, wave-task decomposition -----
// Wave-task = (b, 16-row q-tile, 128-row KV segment): 1-2 iterations each.
// NTPB = sum_qt ceil((qt+1)/8) = 1088; total 8704 tasks, grid 2176.
#define NTPB 1088
__launch_bounds__(256)
__global__ void flash_kernel(const ushort* __restrict__ qg, const ushort* __restrict__ kg,
                             const ushort* __restrict__ vtg, float* __restrict__ out,
                             ushort* __restrict__ pO, float* __restrict__ pM,
                             float* __restrict__ pL) {
    __shared__ ushort Ps[4][16][72];

    int wid  = threadIdx.x >> 6;
    int lane = threadIdx.x & 63;
    int l15  = lane & 15;
    int hi4  = lane >> 4;
    int koff = hi4 * 8;

    int gw = blockIdx.x * 4 + wid;
    int b  = gw / NTPB;
    int tp = gw - b * NTPB;
    int j  = 0;
    while (tp >= 4 * (j + 1) * (j + 2)) j++;     // wave-uniform, <=15 iters
    int r_    = tp - 4 * j * (j + 1);
    int qt    = 8 * j + r_ / (j + 1);
    int seg   = r_ - (qt - 8 * j) * (j + 1);
    int nseg  = j + 1;
    int qmin  = qt * 16;
    int s_beg = seg * 128;
    int s_end = s_beg + 128 < qmin + 16 ? s_beg + 128 : qmin + 16;

    const ushort* qp = qg + ((size_t)b * TT + qmin + l15) * 64 + koff;
    bf16x8 qf0 = __builtin_bit_cast(bf16x8, *(const uint4*)qp);
    bf16x8 qf1 = __builtin_bit_cast(bf16x8, *(const uint4*)(qp + 32));

    f32x4 o[4];
#pragma unroll
    for (int i = 0; i < 4; i++) o[i] = (f32x4){0.f, 0.f, 0.f, 0.f};
    float mrun[4], lpart[4];
#pragma unroll
    for (int r = 0; r < 4; r++) { mrun[r] = -INFINITY; lpart[r] = 0.f; }

    const float scale = 0.125f;

    for (int s0 = s_beg; s0 < s_end; s0 += 64) {
        bool maskt = (s0 + 63 > qmin);

        // K loads first (oldest -> consumed first), V loads stay in flight
        bf16x8 kf[4][2];
#pragma unroll
        for (int nt = 0; nt < 4; nt++) {
            const ushort* kp = kg + ((size_t)b * TT + s0 + nt * 16 + l15) * 64 + koff;
            kf[nt][0] = __builtin_bit_cast(bf16x8, *(const uint4*)kp);
            kf[nt][1] = __builtin_bit_cast(bf16x8, *(const uint4*)(kp + 32));
        }
        bf16x8 vf[4][2];
#pragma unroll
        for (int nth = 0; nth < 4; nth++) {
            const ushort* vbase = vtg + ((size_t)b * 64 + nth * 16 + l15) * TT + s0 + koff;
            vf[nth][0] = __builtin_bit_cast(bf16x8, *(const uint4*)(vbase));
            vf[nth][1] = __builtin_bit_cast(bf16x8, *(const uint4*)(vbase + 32));
        }

        float sv[4][4];
        __builtin_amdgcn_s_setprio(1);
#pragma unroll
        for (int nt = 0; nt < 4; nt++) {
            f32x4 s = (f32x4){0.f, 0.f, 0.f, 0.f};
            s = __builtin_amdgcn_mfma_f32_16x16x32_bf16(qf0, kf[nt][0], s, 0, 0, 0);
            s = __builtin_amdgcn_mfma_f32_16x16x32_bf16(qf1, kf[nt][1], s, 0, 0, 0);
#pragma unroll
            for (int r = 0; r < 4; r++) {
                float v = s[r] * scale;
                if (maskt) {
                    int krow = s0 + nt * 16 + l15;
                    int qgl  = qmin + 4 * hi4 + r;
                    if (krow > qgl) v = -INFINITY;
                }
                sv[nt][r] = v;
            }
        }
        __builtin_amdgcn_s_setprio(0);

        // defer-max: full reduce+rescale only when needed
        float lmax[4];
#pragma unroll
        for (int r = 0; r < 4; r++)
            lmax[r] = fmaxf(fmaxf(sv[0][r], sv[1][r]), fmaxf(sv[2][r], sv[3][r]));
        bool need = (lmax[0] > mrun[0] + 8.f) || (lmax[1] > mrun[1] + 8.f) ||
                    (lmax[2] > mrun[2] + 8.f) || (lmax[3] > mrun[3] + 8.f);
        if (__any(need)) {
#pragma unroll
            for (int r = 0; r < 4; r++) {
                float tmax = lmax[r];
#pragma unroll
                for (int off = 1; off < 16; off <<= 1)
                    tmax = fmaxf(tmax, __shfl_xor(tmax, off));
                float mnew  = fmaxf(mrun[r], tmax);
                float alpha = __expf(mrun[r] - mnew);
                lpart[r] *= alpha;
#pragma unroll
                for (int nth = 0; nth < 4; nth++) o[nth][r] *= alpha;
                mrun[r] = mnew;
            }
        }

        // exp + partial row-sum + P -> LDS (per-wave buffer, same-wave RAW)
#pragma unroll
        for (int r = 0; r < 4; r++) {
            int prow = 4 * hi4 + r;
#pragma unroll
            for (int nt = 0; nt < 4; nt++) {
                float p = __expf(sv[nt][r] - mrun[r]);
                lpart[r] += p;
                Ps[wid][prow][nt * 16 + l15] = f2bits(p);
            }
        }

        bf16x8 pf0 = __builtin_bit_cast(bf16x8, *(const uint4*)&Ps[wid][l15][koff]);
        bf16x8 pf1 = __builtin_bit_cast(bf16x8, *(const uint4*)&Ps[wid][l15][32 + koff]);
        __builtin_amdgcn_s_setprio(1);
#pragma unroll
        for (int nth = 0; nth < 4; nth++) {
            o[nth] = __builtin_amdgcn_mfma_f32_16x16x32_bf16(pf0, vf[nth][0], o[nth], 0, 0, 0);
            o[nth] = __builtin_amdgcn_mfma_f32_16x16x32_bf16(pf1, vf[nth][1], o[nth], 0, 0, 0);
        }
        __builtin_amdgcn_s_setprio(0);
    }

    float lrun[4];
#pragma unroll
    for (int r = 0; r < 4; r++) {
        float s = lpart[r];
#pragma unroll
        for (int off = 1; off < 16; off <<= 1)
            s += __shfl_xor(s, off);
        lrun[r] = s;
    }

    if (nseg == 1) {
        float inv[4];
#pragma unroll
        for (int r = 0; r < 4; r++) inv[r] = 1.0f / lrun[r];
#pragma unroll
        for (int nth = 0; nth < 4; nth++)
#pragma unroll
            for (int r = 0; r < 4; r++) {
                int row = qmin + 4 * hi4 + r;
                out[((size_t)b * TT + row) * 64 + nth * 16 + l15] = o[nth][r] * inv[r];
            }
    } else {
        size_t tb = (size_t)(b * NTPB + tp);
        // bf16 partials, register-order layout: [(nth*64+lane)*4 + r]
#pragma unroll
        for (int nth = 0; nth < 4; nth++) {
            ushort4 pk;
            pk.x = f2bits(o[nth][0]); pk.y = f2bits(o[nth][1]);
            pk.z = f2bits(o[nth][2]); pk.w = f2bits(o[nth][3]);
            *(ushort4*)&pO[tb * 1024 + ((size_t)nth * 64 + lane) * 4] = pk;
        }
        if (l15 == 0) {
#pragma unroll
            for (int r = 0; r < 4; r++) {
                pM[tb * 16 + 4 * hi4 + r] = mrun[r];
                pL[tb * 16 + 4 * hi4 + r] = lrun[r];
            }
        }
    }
}

// ---------------- Kernel 3: merge partials (qt >= 8) ---------------------
__launch_bounds__(256)
__global__ void merge_kernel(const ushort* __restrict__ pO, const float* __restrict__ pM,
                             const float* __restrict__ pL, float* __restrict__ out) {
    int b    = blockIdx.x / 120;
    int qt   = 8 + (blockIdx.x % 120);
    int j    = qt >> 3;
    int nseg = j + 1;
    int tbase = b * NTPB + 4 * j * (j + 1) + (qt - 8 * j) * (j + 1);

    int tid = threadIdx.x;
    int nth = tid >> 6;
    int hi4 = (tid >> 4) & 3;
    int l15 = tid & 15;
    int col = nth * 16 + l15;

    float mstar[4] = {-INFINITY, -INFINITY, -INFINITY, -INFINITY};
    for (int s = 0; s < nseg; s++) {
#pragma unroll
        for (int r = 0; r < 4; r++)
            mstar[r] = fmaxf(mstar[r], pM[(size_t)(tbase + s) * 16 + 4 * hi4 + r]);
    }
    float oa[4] = {0.f, 0.f, 0.f, 0.f};
    float la[4] = {0.f, 0.f, 0.f, 0.f};
    for (int s = 0; s < nseg; s++) {
        float w[4];
#pragma unroll
        for (int r = 0; r < 4; r++) {
            w[r] = __expf(pM[(size_t)(tbase + s) * 16 + 4 * hi4 + r] - mstar[r]);
            la[r] += w[r] * pL[(size_t)(tbase + s) * 16 + 4 * hi4 + r];
        }
        ushort4 pv = *(const ushort4*)&pO[(size_t)(tbase + s) * 1024 +
                                          ((size_t)nth * 64 + hi4 * 16 + l15) * 4];
        oa[0] += w[0] * bits2f(pv.x);
        oa[1] += w[1] * bits2f(pv.y);
        oa[2] += w[2] * bits2f(pv.z);
        oa[3] += w[3] * bits2f(pv.w);
    }
#pragma unroll
    for (int r = 0; r < 4; r++) {
        int row = qt * 16 + 4 * hi4 + r;
        out[((size_t)b * TT + row) * 64 + col] = oa[r] / la[r];
    }
}

// ---------------- launch --------------------------------------------------
extern "C" void kernel_launch(void* const* d_in, const int* in_sizes, int n_in,
                              void* d_out, int out_size, void* d_ws, size_t ws_size,
                              hipStream_t stream) {
    const float* x  = (const float*)d_in[0];
    const float* Wk = (const float*)d_in[1];
    const float* Wq = (const float*)d_in[2];
    const float* Wv = (const float*)d_in[3];
    float* out = (float*)d_out;

    char* ws = (char*)d_ws;
    ushort* Wt  = (ushort*)(ws);                 // 288 KB
    ushort* qws = (ushort*)(ws + 0x50000);       // 2 MB
    ushort* kws = (ushort*)(ws + 0x250000);      // 2 MB
    ushort* vws = (ushort*)(ws + 0x450000);      // 2 MB
    ushort* pO  = (ushort*)(ws + 0x650000);      // 8704*1024*2B = 17.8 MB
    float*  pM  = (float*)(ws + 0x1750000);      // 557 KB
    float*  pL  = (float*)(ws + 0x17D8000);      // 557 KB

    wt_kernel<<<36, 256, 0, stream>>>(Wk, Wq, Wv, Wt);
    qkv_kernel<<<(BB * TT) / 32, 256, 0, stream>>>(x, Wt, qws, kws, vws);
    flash_kernel<<<(BB * NTPB) / 4, 256, 0, stream>>>(qws, kws, vws, out, pO, pM, pL);
    merge_kernel<<<BB * 120, 256, 0, stream>>>(pO, pM, pL, out);
}